// Round 1
// baseline (188.254 us; speedup 1.0000x reference)
//
#include <hip/hip_runtime.h>
#include <hip/hip_bf16.h>
#include <cstdint>

#define DI __device__ __forceinline__

// ---------- bf16 helpers (RNE) ----------
DI float bflo(uint32_t u) { return __builtin_bit_cast(float, (uint32_t)(u << 16)); }
DI float bfhi(uint32_t u) { return __builtin_bit_cast(float, (uint32_t)(u & 0xffff0000u)); }
DI float bf2f(uint16_t u) { return __builtin_bit_cast(float, (uint32_t)((uint32_t)u << 16)); }
DI uint16_t f2bf(float f) {
    uint32_t x = __builtin_bit_cast(uint32_t, f);
    x += 0x7fffu + ((x >> 16) & 1u);
    return (uint16_t)(x >> 16);
}

// ---------- problem constants ----------
constexpr int BATCH = 8, HH_IMG = 56, WW_IMG = 56, C = 192;
constexpr int HEADS = 6, HD = 32, NA = 486;           // heads*81
constexpr int MROWS = BATCH * HH_IMG * WW_IMG;        // 25088

// =======================================================================
// Tiled fp32-accumulate GEMM:  C[M,N] = A[M,K] * W[K,N] (+bias)
// A row-major (fp32 or bf16), W row-major fp32, out bf16 or fp32.
// BM=BN=64, BK=32, 256 threads, 4x4 micro-tile. M % 64 == 0 assumed.
// =======================================================================
constexpr int BM = 64, BN = 64, BK = 32, TM = 4, TN = 4;

template <bool A_BF16, bool OUT_BF16, bool BIAS>
__global__ __launch_bounds__(256) void gemm_k(const void* __restrict__ Ap,
                                              const float* __restrict__ W,
                                              const float* __restrict__ bias,
                                              void* __restrict__ Cp,
                                              int M, int N, int K) {
    __shared__ float As[BK][BM + 4];   // [k][m], +4 pad keeps 16B align & breaks conflicts
    __shared__ float Ws[BK][BN + 4];   // [k][n]
    const int t   = threadIdx.x;
    const int m0  = blockIdx.y * BM;
    const int n0  = blockIdx.x * BN;
    const int ty  = t >> 4, tx = t & 15;
    const int tm0 = ty * TM, tn0 = tx * TN;
    float acc[TM][TN] = {};

    for (int kb = 0; kb < K; kb += BK) {
        // ---- stage A tile (transposed into As[k][m]) ----
        if (A_BF16) {
            const uint16_t* A = (const uint16_t*)Ap;
            const int row = t >> 2, kc = (t & 3) * 8;
            uint4 raw = *(const uint4*)(A + (size_t)(m0 + row) * K + kb + kc);
            uint32_t r[4] = {raw.x, raw.y, raw.z, raw.w};
#pragma unroll
            for (int e = 0; e < 4; e++) {
                As[kc + 2 * e][row]     = bflo(r[e]);
                As[kc + 2 * e + 1][row] = bfhi(r[e]);
            }
        } else {
            const float* A = (const float*)Ap;
#pragma unroll
            for (int l = 0; l < 2; l++) {
                const int fid = t + l * 256;
                const int row = fid >> 3, kc = (fid & 7) * 4;
                float4 v4 = *(const float4*)(A + (size_t)(m0 + row) * K + kb + kc);
                As[kc + 0][row] = v4.x; As[kc + 1][row] = v4.y;
                As[kc + 2][row] = v4.z; As[kc + 3][row] = v4.w;
            }
        }
        // ---- stage W tile (guard N; float2 is always 8B-aligned here) ----
#pragma unroll
        for (int l = 0; l < 4; l++) {
            const int fid = t + l * 256;              // 1024 float2 slots
            const int kr = fid >> 5, nc = (fid & 31) * 2;
            const int gn = n0 + nc;
            float2 v2 = {0.f, 0.f};
            if (gn + 1 < N)  v2 = *(const float2*)(W + (size_t)(kb + kr) * N + gn);
            else if (gn < N) v2.x = W[(size_t)(kb + kr) * N + gn];
            Ws[kr][nc] = v2.x; Ws[kr][nc + 1] = v2.y;
        }
        __syncthreads();
#pragma unroll
        for (int kk = 0; kk < BK; kk++) {
            const float4 a4 = *(const float4*)&As[kk][tm0];
            const float4 b4 = *(const float4*)&Ws[kk][tn0];
            const float av[4] = {a4.x, a4.y, a4.z, a4.w};
            const float bv[4] = {b4.x, b4.y, b4.z, b4.w};
#pragma unroll
            for (int i = 0; i < TM; i++)
#pragma unroll
                for (int j = 0; j < TN; j++)
                    acc[i][j] = fmaf(av[i], bv[j], acc[i][j]);
        }
        __syncthreads();
    }

    // ---- epilogue ----
    if (OUT_BF16) {
        uint16_t* Co = (uint16_t*)Cp;
#pragma unroll
        for (int i = 0; i < TM; i++) {
            const size_t rb = (size_t)(m0 + tm0 + i) * N;
#pragma unroll
            for (int j = 0; j < TN; j += 2) {
                const int gn = n0 + tn0 + j;
                if (gn < N) {  // N even, so gn<N implies gn+1<N
                    float f0 = acc[i][j]     + (BIAS ? bias[gn]     : 0.f);
                    float f1 = acc[i][j + 1] + (BIAS ? bias[gn + 1] : 0.f);
                    uint32_t pk = (uint32_t)f2bf(f0) | ((uint32_t)f2bf(f1) << 16);
                    *(uint32_t*)(Co + rb + gn) = pk;
                }
            }
        }
    } else {
        float* Co = (float*)Cp;
#pragma unroll
        for (int i = 0; i < TM; i++) {
            const size_t rb = (size_t)(m0 + tm0 + i) * N;
#pragma unroll
            for (int j = 0; j < TN; j++) {
                const int gn = n0 + tn0 + j;
                if (gn < N) Co[rb + gn] = acc[i][j] + (BIAS ? bias[gn] : 0.f);
            }
        }
    }
}

// =======================================================================
// Fused softmax + attention + fold (gather form):
//  y_pre[P][n*32+d] = sum_{k=(i,j)} sum_q softmax_q(scale*alog[p][n][k][:])[q]
//                                   * v[P + q - k][n*32+d],  p = P - k + 1
// Each A-row (p,n,k) is used by exactly one target thread -> softmax stays
// in registers. v staged in LDS with +-2 halo (zero padded), bf16, +8 pad.
// Tile 4x8 pixels, 192 threads = 32 px * 6 heads.
// =======================================================================
constexpr int TH = 4, TW = 8;
constexpr int HALO_H = TH + 4, HALO_W = TW + 4;   // 8 x 12
constexpr int VSTR = C + 8;                       // 200 bf16 (400B, 16B-mult)

__global__ __launch_bounds__(192) void attn_fold_k(const uint16_t* __restrict__ v,
                                                   const uint16_t* __restrict__ alog,
                                                   uint16_t* __restrict__ ypre) {
    __shared__ uint16_t vl[HALO_H * HALO_W][VSTR];   // 38.4 KB
    const int b   = blockIdx.z;
    const int ty0 = blockIdx.y * TH, tx0 = blockIdx.x * TW;
    const int t   = threadIdx.x;

    // ---- stage v halo (zero-pad OOB), vectorized 8 bf16 per load ----
    for (int l = t; l < HALO_H * HALO_W * (C / 8); l += 192) {
        const int px = l / (C / 8), c8 = (l % (C / 8)) * 8;
        const int hy = px / HALO_W, hx = px % HALO_W;
        const int y = ty0 + hy - 2, x = tx0 + hx - 2;
        uint4 val = make_uint4(0u, 0u, 0u, 0u);
        if (y >= 0 && y < HH_IMG && x >= 0 && x < WW_IMG)
            val = *(const uint4*)&v[(((size_t)b * HH_IMG + y) * WW_IMG + x) * C + c8];
        *(uint4*)&vl[px][c8] = val;
    }

    const int n   = t % HEADS, pxl = t / HEADS;      // (head, pixel-in-tile)
    const int py  = pxl / TW, px_ = pxl % TW;
    const int Py  = ty0 + py, Px = tx0 + px_;
    const float scale = 0.17677669529663687f;        // 32^-0.5
    float acc[HD] = {};
    __syncthreads();

#pragma unroll 1
    for (int i = 0; i < 3; i++)
#pragma unroll 1
        for (int j = 0; j < 3; j++) {
            const int sy = Py - i + 1, sx = Px - j + 1;   // source pixel p
            float w[9];
            if (sy >= 0 && sy < HH_IMG && sx >= 0 && sx < WW_IMG) {
                const uint16_t* ap = alog + (((size_t)b * HH_IMG + sy) * WW_IMG + sx) * NA
                                   + n * 81 + (i * 3 + j) * 9;
                float L[9], mx = -1e30f;
#pragma unroll
                for (int q = 0; q < 9; q++) { L[q] = bf2f(ap[q]) * scale; mx = fmaxf(mx, L[q]); }
                float s = 0.f;
#pragma unroll
                for (int q = 0; q < 9; q++) { w[q] = __expf(L[q] - mx); s += w[q]; }
                const float inv = 1.f / s;
#pragma unroll
                for (int q = 0; q < 9; q++) w[q] *= inv;
            } else {
#pragma unroll
                for (int q = 0; q < 9; q++) w[q] = 0.f;
            }
#pragma unroll
            for (int qi = 0; qi < 3; qi++)
#pragma unroll
                for (int qj = 0; qj < 3; qj++) {
                    const float wq = w[qi * 3 + qj];
                    const uint16_t* vp = &vl[(py + 2 + qi - i) * HALO_W + (px_ + 2 + qj - j)][n * HD];
#pragma unroll
                    for (int v8 = 0; v8 < 4; v8++) {
                        const uint4 raw = *(const uint4*)&vp[v8 * 8];
                        const uint32_t r0 = raw.x, r1 = raw.y, r2 = raw.z, r3 = raw.w;
                        acc[v8*8+0] = fmaf(wq, bflo(r0), acc[v8*8+0]);
                        acc[v8*8+1] = fmaf(wq, bfhi(r0), acc[v8*8+1]);
                        acc[v8*8+2] = fmaf(wq, bflo(r1), acc[v8*8+2]);
                        acc[v8*8+3] = fmaf(wq, bfhi(r1), acc[v8*8+3]);
                        acc[v8*8+4] = fmaf(wq, bflo(r2), acc[v8*8+4]);
                        acc[v8*8+5] = fmaf(wq, bfhi(r2), acc[v8*8+5]);
                        acc[v8*8+6] = fmaf(wq, bflo(r3), acc[v8*8+6]);
                        acc[v8*8+7] = fmaf(wq, bfhi(r3), acc[v8*8+7]);
                    }
                }
        }

    // ---- store y_pre (bf16, packed dword stores) ----
    uint16_t* op = ypre + (((size_t)b * HH_IMG + Py) * WW_IMG + Px) * C + n * HD;
#pragma unroll
    for (int d = 0; d < HD; d += 2) {
        const uint32_t pk = (uint32_t)f2bf(acc[d]) | ((uint32_t)f2bf(acc[d + 1]) << 16);
        *(uint32_t*)&op[d] = pk;
    }
}

// =======================================================================
extern "C" void kernel_launch(void* const* d_in, const int* in_sizes, int n_in,
                              void* d_out, int out_size, void* d_ws, size_t ws_size,
                              hipStream_t stream) {
    const float* x  = (const float*)d_in[0];
    const float* Wv = (const float*)d_in[1];
    const float* Wa = (const float*)d_in[2];
    const float* ba = (const float*)d_in[3];
    const float* Wp = (const float*)d_in[4];
    const float* bp = (const float*)d_in[5];
    float* out = (float*)d_out;

    // workspace layout (bf16): v[25088*192] | alog[25088*486] | ypre[25088*192]
    uint16_t* v    = (uint16_t*)d_ws;
    uint16_t* alog = v + (size_t)MROWS * C;
    uint16_t* ypre = alog + (size_t)MROWS * NA;

    const dim3 blk(256);
    // v = x @ Wv                       (fp32 in, bf16 out)
    gemm_k<false, true, false><<<dim3(C / BN, MROWS / BM), blk, 0, stream>>>(
        x, Wv, nullptr, v, MROWS, C, C);
    // alog = x @ Wa + ba               (fp32 in, bf16 out, N=486 guarded)
    gemm_k<false, true, true><<<dim3((NA + BN - 1) / BN, MROWS / BM), blk, 0, stream>>>(
        x, Wa, ba, alog, MROWS, NA, C);
    // softmax + attn + fold            -> ypre (bf16)
    attn_fold_k<<<dim3(WW_IMG / TW, HH_IMG / TH, BATCH), dim3(192), 0, stream>>>(
        v, alog, ypre);
    // out = ypre @ Wp + bp             (bf16 in, fp32 out)
    gemm_k<true, false, true><<<dim3(C / BN, MROWS / BM), blk, 0, stream>>>(
        ypre, Wp, bp, out, MROWS, C, C);
}

// Round 2
// 113.195 us; speedup vs baseline: 1.6631x; 1.6631x over previous
//
#include <hip/hip_runtime.h>
#include <hip/hip_bf16.h>
#include <cstdint>

#define DI __device__ __forceinline__

typedef __attribute__((ext_vector_type(8))) short short8;
typedef __attribute__((ext_vector_type(4))) float f32x4;

// ---------- bf16 helpers (RNE) ----------
DI float bflo(uint32_t u) { return __builtin_bit_cast(float, (uint32_t)(u << 16)); }
DI float bfhi(uint32_t u) { return __builtin_bit_cast(float, (uint32_t)(u & 0xffff0000u)); }
DI float bf2f(uint16_t u) { return __builtin_bit_cast(float, (uint32_t)((uint32_t)u << 16)); }
DI uint16_t f2bf(float f) {
    uint32_t x = __builtin_bit_cast(uint32_t, f);
    x += 0x7fffu + ((x >> 16) & 1u);
    return (uint16_t)(x >> 16);
}
DI uint32_t pk2bf(float a, float b) {
    return (uint32_t)f2bf(a) | ((uint32_t)f2bf(b) << 16);
}

// ---------- problem constants ----------
constexpr int BATCH = 8, HH_IMG = 56, WW_IMG = 56, C = 192;
constexpr int HEADS = 6, HD = 32, NA = 486;
constexpr int MROWS = BATCH * HH_IMG * WW_IMG;        // 25088

// =======================================================================
// MFMA GEMM: C[M,N] = A[M,K] * W[K,N] (+bias), fp32 accum via
// v_mfma_f32_16x16x32_bf16. A fp32 or bf16 (row-major), W fp32 row-major.
// Tile BM=128, BN=64, BK=64. 256 thr = 4 waves (2x2), wave = 64x32 out.
// LDS: A[128][64] bf16, B stored transposed [64 n][64 k] bf16; both with
// byte ^= (row&7)<<4 XOR swizzle (reads AND writes bijective per 16B slot).
// Requires M%128==0, K%64==0. N guarded.
// =======================================================================
template <bool A_BF16, bool OUT_BF16, bool BIAS>
__global__ __launch_bounds__(256) void gemm_mfma(const void* __restrict__ Ap,
                                                 const float* __restrict__ W,
                                                 const float* __restrict__ bias,
                                                 void* __restrict__ Cp,
                                                 int M, int N, int K) {
    __shared__ __align__(16) uint8_t sm[128 * 128 + 64 * 128];   // A 16KB | B 8KB
    uint8_t* Asm = sm;
    uint8_t* Bsm = sm + 128 * 128;

    const int t  = threadIdx.x;
    const int m0 = blockIdx.y * 128, n0 = blockIdx.x * 64;
    const int l  = t & 63, wid = t >> 6;
    const int wr = wid >> 1, wc = wid & 1;      // wave quadrant: rows wr*64, cols wc*32
    const int lr = l & 15, lg = l >> 4;

    f32x4 acc[4][2];
#pragma unroll
    for (int i = 0; i < 4; i++)
#pragma unroll
        for (int j = 0; j < 2; j++) acc[i][j] = f32x4{0.f, 0.f, 0.f, 0.f};

    for (int kb = 0; kb < K; kb += 64) {
        __syncthreads();   // protect LDS from previous iteration's readers
        // ---- stage A: 128 rows x 64 k (2 threads/row, 32 k each) ----
        {
            const int m = t >> 1, kh = t & 1;
            const int rowb = m * 128, colb = kh * 64, sw = (m & 7) << 4;
            if (A_BF16) {
                const uint16_t* A = (const uint16_t*)Ap + (size_t)(m0 + m) * K + kb + kh * 32;
#pragma unroll
                for (int w = 0; w < 4; ++w) {
                    uint4 o = ((const uint4*)A)[w];
                    *(uint4*)(Asm + rowb + ((colb + w * 16) ^ sw)) = o;
                }
            } else {
                const float* A = (const float*)Ap + (size_t)(m0 + m) * K + kb + kh * 32;
#pragma unroll
                for (int w = 0; w < 4; ++w) {
                    const float4 v0 = ((const float4*)A)[w * 2];
                    const float4 v1 = ((const float4*)A)[w * 2 + 1];
                    uint4 o;
                    o.x = pk2bf(v0.x, v0.y); o.y = pk2bf(v0.z, v0.w);
                    o.z = pk2bf(v1.x, v1.y); o.w = pk2bf(v1.z, v1.w);
                    *(uint4*)(Asm + rowb + ((colb + w * 16) ^ sw)) = o;
                }
            }
        }
        // ---- stage B transposed: thread owns col n, 16 k rows (coalesced) ----
        {
            const int n = t & 63, kq = t >> 6;
            const bool valid = (n0 + n) < N;
            const float* Wf = W + (size_t)(kb + kq * 16) * N + n0 + n;
            uint32_t pk[8];
#pragma unroll
            for (int e = 0; e < 8; ++e) {
                const float f0 = valid ? Wf[(size_t)(2 * e) * N]     : 0.f;
                const float f1 = valid ? Wf[(size_t)(2 * e + 1) * N] : 0.f;
                pk[e] = pk2bf(f0, f1);
            }
            const int rowb = n * 128, colb = kq * 32, sw = (n & 7) << 4;
            *(uint4*)(Bsm + rowb + ((colb)      ^ sw)) = make_uint4(pk[0], pk[1], pk[2], pk[3]);
            *(uint4*)(Bsm + rowb + ((colb + 16) ^ sw)) = make_uint4(pk[4], pk[5], pk[6], pk[7]);
        }
        __syncthreads();
        // ---- compute: 2 k-halves of 32, 8 MFMA each ----
#pragma unroll
        for (int kk = 0; kk < 2; ++kk) {
            const int cb = kk * 64 + lg * 16;
            short8 a[4], b[2];
#pragma unroll
            for (int mr = 0; mr < 4; ++mr) {
                const int row = wr * 64 + mr * 16 + lr;
                a[mr] = *(const short8*)(Asm + row * 128 + (cb ^ ((row & 7) << 4)));
            }
#pragma unroll
            for (int nr = 0; nr < 2; ++nr) {
                const int rn = wc * 32 + nr * 16 + lr;
                b[nr] = *(const short8*)(Bsm + rn * 128 + (cb ^ ((rn & 7) << 4)));
            }
#pragma unroll
            for (int mr = 0; mr < 4; ++mr)
#pragma unroll
                for (int nr = 0; nr < 2; ++nr)
                    acc[mr][nr] = __builtin_amdgcn_mfma_f32_16x16x32_bf16(
                        a[mr], b[nr], acc[mr][nr], 0, 0, 0);
        }
    }

    // ---- epilogue: D col = lane&15, row = 4*(lane>>4)+reg ----
#pragma unroll
    for (int nr = 0; nr < 2; ++nr) {
        const int col = n0 + wc * 32 + nr * 16 + lr;
        if (col >= N) continue;
        const float bv = BIAS ? bias[col] : 0.f;
#pragma unroll
        for (int mr = 0; mr < 4; ++mr) {
            const size_t rowb = (size_t)(m0 + wr * 64 + mr * 16 + lg * 4);
#pragma unroll
            for (int j = 0; j < 4; ++j) {
                const float val = acc[mr][nr][j] + bv;
                if (OUT_BF16)
                    ((uint16_t*)Cp)[(rowb + j) * N + col] = f2bf(val);
                else
                    ((float*)Cp)[(rowb + j) * N + col] = val;
            }
        }
    }
}

// =======================================================================
// Fused softmax + attention + fold (gather form) — unchanged from round 1.
// =======================================================================
constexpr int TH = 4, TW = 8;
constexpr int HALO_H = TH + 4, HALO_W = TW + 4;   // 8 x 12
constexpr int VSTR = C + 8;                       // 200 bf16

__global__ __launch_bounds__(192) void attn_fold_k(const uint16_t* __restrict__ v,
                                                   const uint16_t* __restrict__ alog,
                                                   uint16_t* __restrict__ ypre) {
    __shared__ uint16_t vl[HALO_H * HALO_W][VSTR];   // 38.4 KB
    const int b   = blockIdx.z;
    const int ty0 = blockIdx.y * TH, tx0 = blockIdx.x * TW;
    const int t   = threadIdx.x;

    for (int l = t; l < HALO_H * HALO_W * (C / 8); l += 192) {
        const int px = l / (C / 8), c8 = (l % (C / 8)) * 8;
        const int hy = px / HALO_W, hx = px % HALO_W;
        const int y = ty0 + hy - 2, x = tx0 + hx - 2;
        uint4 val = make_uint4(0u, 0u, 0u, 0u);
        if (y >= 0 && y < HH_IMG && x >= 0 && x < WW_IMG)
            val = *(const uint4*)&v[(((size_t)b * HH_IMG + y) * WW_IMG + x) * C + c8];
        *(uint4*)&vl[px][c8] = val;
    }

    const int n   = t % HEADS, pxl = t / HEADS;
    const int py  = pxl / TW, px_ = pxl % TW;
    const int Py  = ty0 + py, Px = tx0 + px_;
    const float scale = 0.17677669529663687f;        // 32^-0.5
    float acc[HD] = {};
    __syncthreads();

#pragma unroll 1
    for (int i = 0; i < 3; i++)
#pragma unroll 1
        for (int j = 0; j < 3; j++) {
            const int sy = Py - i + 1, sx = Px - j + 1;
            float w[9];
            if (sy >= 0 && sy < HH_IMG && sx >= 0 && sx < WW_IMG) {
                const uint16_t* ap = alog + (((size_t)b * HH_IMG + sy) * WW_IMG + sx) * NA
                                   + n * 81 + (i * 3 + j) * 9;
                float L[9], mx = -1e30f;
#pragma unroll
                for (int q = 0; q < 9; q++) { L[q] = bf2f(ap[q]) * scale; mx = fmaxf(mx, L[q]); }
                float s = 0.f;
#pragma unroll
                for (int q = 0; q < 9; q++) { w[q] = __expf(L[q] - mx); s += w[q]; }
                const float inv = 1.f / s;
#pragma unroll
                for (int q = 0; q < 9; q++) w[q] *= inv;
            } else {
#pragma unroll
                for (int q = 0; q < 9; q++) w[q] = 0.f;
            }
#pragma unroll
            for (int qi = 0; qi < 3; qi++)
#pragma unroll
                for (int qj = 0; qj < 3; qj++) {
                    const float wq = w[qi * 3 + qj];
                    const uint16_t* vp = &vl[(py + 2 + qi - i) * HALO_W + (px_ + 2 + qj - j)][n * HD];
#pragma unroll
                    for (int v8 = 0; v8 < 4; v8++) {
                        const uint4 raw = *(const uint4*)&vp[v8 * 8];
                        const uint32_t r0 = raw.x, r1 = raw.y, r2 = raw.z, r3 = raw.w;
                        acc[v8*8+0] = fmaf(wq, bflo(r0), acc[v8*8+0]);
                        acc[v8*8+1] = fmaf(wq, bfhi(r0), acc[v8*8+1]);
                        acc[v8*8+2] = fmaf(wq, bflo(r1), acc[v8*8+2]);
                        acc[v8*8+3] = fmaf(wq, bfhi(r1), acc[v8*8+3]);
                        acc[v8*8+4] = fmaf(wq, bflo(r2), acc[v8*8+4]);
                        acc[v8*8+5] = fmaf(wq, bfhi(r2), acc[v8*8+5]);
                        acc[v8*8+6] = fmaf(wq, bflo(r3), acc[v8*8+6]);
                        acc[v8*8+7] = fmaf(wq, bfhi(r3), acc[v8*8+7]);
                    }
                }
        }

    uint16_t* op = ypre + (((size_t)b * HH_IMG + Py) * WW_IMG + Px) * C + n * HD;
#pragma unroll
    for (int d = 0; d < HD; d += 2) {
        const uint32_t pk = (uint32_t)f2bf(acc[d]) | ((uint32_t)f2bf(acc[d + 1]) << 16);
        *(uint32_t*)&op[d] = pk;
    }
}

// =======================================================================
extern "C" void kernel_launch(void* const* d_in, const int* in_sizes, int n_in,
                              void* d_out, int out_size, void* d_ws, size_t ws_size,
                              hipStream_t stream) {
    const float* x  = (const float*)d_in[0];
    const float* Wv = (const float*)d_in[1];
    const float* Wa = (const float*)d_in[2];
    const float* ba = (const float*)d_in[3];
    const float* Wp = (const float*)d_in[4];
    const float* bp = (const float*)d_in[5];
    float* out = (float*)d_out;

    // workspace (bf16): v[25088*192] | alog[25088*486] | ypre[25088*192]
    uint16_t* v    = (uint16_t*)d_ws;
    uint16_t* alog = v + (size_t)MROWS * C;
    uint16_t* ypre = alog + (size_t)MROWS * NA;

    // v = x @ Wv                     (fp32 in, bf16 out)
    gemm_mfma<false, true, false><<<dim3(C / 64, MROWS / 128), 256, 0, stream>>>(
        x, Wv, nullptr, v, MROWS, C, C);
    // alog = x @ Wa + ba             (fp32 in, bf16 out, N=486 guarded)
    gemm_mfma<false, true, true><<<dim3((NA + 63) / 64, MROWS / 128), 256, 0, stream>>>(
        x, Wa, ba, alog, MROWS, NA, C);
    // softmax + attn + fold          -> ypre (bf16)
    attn_fold_k<<<dim3(WW_IMG / TW, HH_IMG / TH, BATCH), dim3(192), 0, stream>>>(
        v, alog, ypre);
    // out = ypre @ Wp + bp           (bf16 in, fp32 out)
    gemm_mfma<true, false, true><<<dim3(C / 64, MROWS / 128), 256, 0, stream>>>(
        ypre, Wp, bp, out, MROWS, C, C);
}